// Round 10
// baseline (463.807 us; speedup 1.0000x reference)
//
#include <hip/hip_runtime.h>
#include <math.h>

#define BB  64
#define CC  512
#define NN  4
#define KK  1024
#define DD  128
#define HW  1024
#define PP  65536

// d_out layout (float32, concatenated in return order)
#define OFF_DIFF 33554432UL
#define OFF_ARG  33554433UL
#define OFF_PPL  33816577UL

// d_ws layout (bytes)
#define WS_HIST   0
#define WS_DSUM   16384
#define WS_WLCNT  16392
#define WS_FIN    16396
#define WS_ENORM  16416
#define WS_EBF    32800                          // 128 tiles * 8192 B = 1 MiB (pre-swizzled fp16 eh, 32 codes x 128 d)
#define WS_EMBT   (32800 + 128*8192)             // fp32 embed_t[n][k][d], 2 MiB
#define WS_WL     (WS_EMBT + NN*KK*DD*4)

#define DELTA 0.0625f   // near-tie margin (dist space) -> fp64 re-check

typedef _Float16 half8 __attribute__((ext_vector_type(8)));
typedef float f32x4 __attribute__((ext_vector_type(4)));

#define MFMA16(a, b, c) __builtin_amdgcn_mfma_f32_16x16x32_f16(a, b, c, 0, 0, 0)

// swizzled byte offset for [row][128 fp16] tiles (256B rows): XOR 16B-slot with row&15
__device__ __forceinline__ int swz(int row, int dbyte) {
    return (row * 256 + dbyte) ^ ((row & 15) << 4);
}
__device__ __forceinline__ void gl2lds16(const void* g, void* l) {
    __builtin_amdgcn_global_load_lds(
        (const __attribute__((address_space(1))) unsigned int*)g,
        (__attribute__((address_space(3))) unsigned int*)l, 16, 0, 0);
}

// ---- prep: embed -> pre-swizzled fp16 tiles + fp32 embed_t + (-enorm/2) ----
__global__ __launch_bounds__(256) void vq_prep(const float* __restrict__ embed,
                                               char* __restrict__ ebf,
                                               float* __restrict__ embt,
                                               float* __restrict__ enorm,
                                               unsigned* __restrict__ hist,
                                               double* __restrict__ dsum,
                                               unsigned* __restrict__ wlcnt,
                                               unsigned* __restrict__ fincnt) {
    __shared__ float sred[4][64];
    const int e = blockIdx.x, n = e >> 4, kt = e & 15, k0 = kt * 64;
    const int t = threadIdx.x, kr = t & 63, dc = t >> 6;   // 4 d-chunks of 32
    if (t < 64) hist[e * 64 + t] = 0u;
    if (e == 0 && t == 0) { *dsum = 0.0; *wlcnt = 0u; *fincnt = 0u; }

    const float* src = embed + ((size_t)n * DD + dc * 32) * KK + k0 + kr;
    char* tile = ebf + ((size_t)(n * 32 + kt * 2 + (kr >> 5))) * 8192;
    const int row = kr & 31;
    float fv[32];
    #pragma unroll
    for (int r = 0; r < 32; ++r) fv[r] = src[(size_t)r * KK];
    float s = 0.f;
    #pragma unroll
    for (int j = 0; j < 4; ++j) {
        half8 vh;
        #pragma unroll
        for (int r = 0; r < 8; ++r) {
            float f = fv[j * 8 + r];
            vh[r] = (_Float16)f;
            s = fmaf(f, f, s);
        }
        *(half8*)(tile + swz(row, (dc * 32 + j * 8) * 2)) = vh;
    }
    {   // fp32 transposed codebook row for epilogue/refine
        float* drow = embt + ((size_t)n * KK + k0 + kr) * DD + dc * 32;
        #pragma unroll
        for (int j = 0; j < 8; ++j)
            *(float4*)(drow + j * 4) = make_float4(fv[j*4], fv[j*4+1], fv[j*4+2], fv[j*4+3]);
    }
    sred[dc][kr] = s;
    __syncthreads();
    if (t < 64) enorm[n * KK + k0 + t] =
        -0.5f * ((sred[0][t] + sred[1][t]) + (sred[2][t] + sred[3][t]));
}

// top-2 (MAX semantics on acc = z.e - e2/2; dist = -2*acc); static indices
#define TOP2(C0, C1, MF, KP)                                                  \
    _Pragma("unroll")                                                         \
    for (int i_ = 0; i_ < 4; ++i_) {                                          \
        float v_ = C0[i_] + C1[i_];                                           \
        int r_ = (MF) * 4 + i_;                                               \
        float mn_ = fminf(pb1[r_], v_);                                       \
        pb2[r_] = fmaxf(pb2[r_], mn_);                                        \
        pk1[r_] = (v_ > pb1[r_]) ? (KP) : pk1[r_];                            \
        pb1[r_] = fmaxf(pb1[r_], v_);                                         \
    }

// one tile step: stage-first (issue early), ds_read B, 8 MFMA -> ACW, TOP2(ACR prev)
#define VSTEP(ACW, ACR, KTL, KPREV)                                           \
  {                                                                           \
    if (gW < 128) {                                                           \
        const char* s_ = ebf + (size_t)gW * 8192 + t * 16;                    \
        char* d_ = ebase + (bufW << 13) + t * 16;                             \
        gl2lds16(s_, d_);                                                     \
        gl2lds16(s_ + 4096, d_ + 4096);                                       \
    }                                                                         \
    ++gW; bufW = (bufW == 5) ? 0 : bufW + 1;                                  \
    const int rb_ = bufR << 13;                                               \
    bufR = (bufR == 5) ? 0 : bufR + 1;                                        \
    half8 bh0 = *(const half8*)(ebase + rb_ + bo0);                           \
    half8 bh1 = *(const half8*)(ebase + rb_ + bo1);                           \
    half8 bh2 = *(const half8*)(ebase + rb_ + bo2);                           \
    half8 bh3 = *(const half8*)(ebase + rb_ + bo3);                           \
    float e2a = enls[((KTL) << 5) + koff];                                    \
    f32x4 e2v = {e2a, e2a, e2a, e2a};                                         \
    ACW##00 = MFMA16(af[0][0], bh0, e2v);                                     \
    ACW##00 = MFMA16(af[0][1], bh1, ACW##00);                                 \
    ACW##01 = MFMA16(af[0][2], bh2, zz4);                                     \
    ACW##01 = MFMA16(af[0][3], bh3, ACW##01);                                 \
    ACW##10 = MFMA16(af[1][0], bh0, e2v);                                     \
    ACW##10 = MFMA16(af[1][1], bh1, ACW##10);                                 \
    ACW##11 = MFMA16(af[1][2], bh2, zz4);                                     \
    ACW##11 = MFMA16(af[1][3], bh3, ACW##11);                                 \
    TOP2(ACR##00, ACR##01, 0, KPREV);                                         \
    TOP2(ACR##10, ACR##11, 1, KPREV);                                         \
  }

// ---- main ------------------------------------------------------------------
// 64 pos/block, 256 thr = 4 waves (2 p-halves x 2 k-halves); 6 LDS e-buffers,
// prefetch distance 4, one barrier + counted vmcnt per 2 tiles; acc ping-pong.
// Tail: FINAL window (n==3, wnd==15) has <=4 outstanding loads -> vmcnt(0) there.
__global__ __launch_bounds__(256, 2) void vq_main(const float* __restrict__ x,
                                                  const char* __restrict__ ebf,
                                                  const float* __restrict__ embt,
                                                  const float* __restrict__ enormg,
                                                  float* __restrict__ out,
                                                  unsigned* __restrict__ hist,
                                                  double* __restrict__ dsum,
                                                  unsigned* __restrict__ wlcnt,
                                                  int2* __restrict__ wl, int wlcap) {
    __shared__ __attribute__((aligned(16))) _Float16 zs[64 * 128];      // 16KB
    __shared__ __attribute__((aligned(16))) char ebuf[6][8192];         // 48KB
    __shared__ __attribute__((aligned(16))) float enls[KK];             // 4KB (-enorm/2)
    __shared__ int   idx_s[NN][64];
    __shared__ float red_b1[2][64], red_b2[2][64];
    __shared__ int   red_k1[2][64];
    __shared__ float wsum[4];

    const int t   = threadIdx.x;
    const int blk = blockIdx.x;                 // 1024 blocks: 16 per batch
    const int b   = blk >> 4;
    const int hw0 = (blk & 15) << 6;            // 64 consecutive positions
    const int w  = t >> 6, l = t & 63;
    const int pq = w >> 1;                      // p-half (32 rows)
    const int ks = w & 1;                       // k-half (16 of 32 per tile)
    const int tk = l & 15, lg = l >> 4;
    const int koff = ks * 16 + tk;

    char* ebase = (char*)&ebuf[0][0];
    const int bo0 = swz(koff, (0 * 32 + lg * 8) * 2);
    const int bo1 = swz(koff, (1 * 32 + lg * 8) * 2);
    const int bo2 = swz(koff, (2 * 32 + lg * 8) * 2);
    const int bo3 = swz(koff, (3 * 32 + lg * 8) * 2);

    const f32x4 zz4 = {0.f, 0.f, 0.f, 0.f};
    const f32x4 m1e30 = {-1e30f, -1e30f, -1e30f, -1e30f};

    int bufR = 0, bufW = 4, gW = 4;             // tile g -> buffer g%6, maintained incrementally
    float znacc = 0.f, sumb1 = 0.f;

    for (int n = 0; n < NN; ++n) {
        __syncthreads();                        // (A) zs/enls/red/idx reuse guard
        // stage -enorm/2 slice for this n (4KB)
        gl2lds16((const char*)(enormg + n * KK) + t * 16, (char*)enls + t * 16);
        if (n == 0) {                           // prologue: tiles 0..3 -> bufs 0..3
            #pragma unroll
            for (int j = 0; j < 4; ++j) {
                const char* s_ = ebf + (size_t)j * 8192 + t * 16;
                char* d_ = ebase + j * 8192 + t * 16;
                gl2lds16(s_, d_);
                gl2lds16(s_ + 4096, d_ + 4096);
            }
        }
        // ---- stage z (fp32 -> fp16 single-term, swizzled)
        {
            const int p = t & 63, dchunk = t >> 6;
            const float* xp = x + ((size_t)b * CC + n * DD + dchunk * 32) * HW + hw0 + p;
            float fv[32];
            #pragma unroll
            for (int r = 0; r < 32; ++r) fv[r] = xp[(size_t)r * HW];
            #pragma unroll
            for (int j = 0; j < 4; ++j) {
                half8 vh;
                #pragma unroll
                for (int r = 0; r < 8; ++r) {
                    float f = fv[j * 8 + r];
                    vh[r] = (_Float16)f;
                    znacc = fmaf(f, f, znacc);
                }
                *(half8*)((char*)zs + swz(p, (dchunk * 32 + j * 8) * 2)) = vh;
            }
        }
        __syncthreads();                        // (B) full drain: zs+enls+tiles resident

        // ---- A-fragments in registers for the whole n (8 frags = 32 VGPR)
        half8 af[2][4];
        #pragma unroll
        for (int mf = 0; mf < 2; ++mf)
            #pragma unroll
            for (int ds = 0; ds < 4; ++ds)
                af[mf][ds] = *(const half8*)((const char*)zs +
                               swz(pq * 32 + mf * 16 + tk, (ds * 32 + lg * 8) * 2));

        float pb1[8], pb2[8]; int pk1[8];       // r = mf*4+i -> p = pq*32+mf*16+lg*4+i
        #pragma unroll
        for (int r = 0; r < 8; ++r) { pb1[r] = -INFINITY; pb2[r] = -INFINITY; pk1[r] = 0; }

        f32x4 accA00, accA01, accA10, accA11;
        f32x4 accB00 = m1e30, accB01 = m1e30, accB10 = m1e30, accB11 = m1e30;

        #pragma unroll 1
        for (int wnd = 0; wnd < 16; ++wnd) {
            if (n == NN - 1 && wnd == 15)
                asm volatile("s_waitcnt vmcnt(0)" ::: "memory");   // tail: nothing left staging
            else
                asm volatile("s_waitcnt vmcnt(4)" ::: "memory");   // completes the 2 tiles read below
            __builtin_amdgcn_s_barrier();
            __builtin_amdgcn_sched_barrier(0);
            const int ka = wnd * 2;
            VSTEP(accA, accB, ka,     ((ka - 1) << 5) + koff)
            VSTEP(accB, accA, ka + 1, (ka << 5) + koff)
        }
        TOP2(accB00, accB01, 0, (31 << 5) + koff);   // drain tile 31
        TOP2(accB10, accB11, 1, (31 << 5) + koff);

        // ---- merge across the 16 lane-columns (tk) of the wave (max semantics)
        #pragma unroll
        for (int off = 1; off < 16; off <<= 1) {
            #pragma unroll
            for (int r = 0; r < 8; ++r) {
                float ob1 = __shfl_xor(pb1[r], off);
                float ob2 = __shfl_xor(pb2[r], off);
                int   ok1 = __shfl_xor(pk1[r], off);
                float nb2 = fmaxf(pb2[r], ob2);
                if (ob1 > pb1[r] || (ob1 == pb1[r] && ok1 < pk1[r])) {
                    pb2[r] = fmaxf(nb2, pb1[r]); pb1[r] = ob1; pk1[r] = ok1;
                } else {
                    pb2[r] = fmaxf(nb2, ob1);
                }
            }
        }
        if (tk == 0) {
            #pragma unroll
            for (int mf = 0; mf < 2; ++mf)
                #pragma unroll
                for (int i = 0; i < 4; ++i) {
                    int p = pq * 32 + mf * 16 + lg * 4 + i, r = mf * 4 + i;
                    red_b1[ks][p] = pb1[r]; red_b2[ks][p] = pb2[r]; red_k1[ks][p] = pk1[r];
                }
        }
        __syncthreads();
        if (t < 64) {                           // merge the 2 k-halves
            int p = t;
            float m1 = red_b1[0][p], m2 = red_b2[0][p]; int mk = red_k1[0][p];
            {
                float ob1 = red_b1[1][p], ob2 = red_b2[1][p]; int ok = red_k1[1][p];
                float nb2 = fmaxf(m2, ob2);
                if (ob1 > m1 || (ob1 == m1 && ok < mk)) { m2 = fmaxf(nb2, m1); m1 = ob1; mk = ok; }
                else                                    { m2 = fmaxf(nb2, ob1); }
            }
            idx_s[n][p] = mk;
            atomicAdd(&hist[n * KK + mk], 1u);
            sumb1 += m1;                        // dist = -2*m1; diff adds znorm separately
            if ((m1 - m2) < DELTA * 0.5f) {     // dist margin = 2*(m1-m2)
                unsigned pos = atomicAdd(wlcnt, 1u);
                if ((int)pos < wlcap) wl[pos] = make_int2(b * HW + hw0 + p, n);
            }
        }
    }

    // ---- diff partial reduce
    {
        float tot = znacc - 2.f * sumb1;
        #pragma unroll
        for (int off = 32; off > 0; off >>= 1) tot += __shfl_down(tot, off);
        if (l == 0) wsum[w] = tot;
        __syncthreads();                        // also guards idx_s for epilogue
        if (t == 0) {
            double sd = 0.0;
            #pragma unroll
            for (int ww = 0; ww < 4; ++ww) sd += (double)wsum[ww];
            atomicAdd(dsum, sd);
        }
    }

    // ---- argmin output (as float)
    {
        int n2 = t >> 6, p = t & 63;
        out[OFF_ARG + (size_t)b * (NN * HW) + (size_t)n2 * HW + hw0 + p] = (float)idx_s[n2][p];
    }

    // ---- z_q gather: contiguous embed_t rows (L2-resident) + coalesced stores
    {
        const int p = t & 63, dchunk = t >> 6;
        #pragma unroll
        for (int n2 = 0; n2 < NN; ++n2) {
            int k = idx_s[n2][p];
            const float4* src = (const float4*)(embt + ((size_t)n2 * KK + k) * DD + dchunk * 32);
            const int c0 = n2 * 128 + dchunk * 32;
            #pragma unroll
            for (int r = 0; r < 8; ++r) {
                float4 q = src[r];
                out[((size_t)b * CC + c0 + r * 4 + 0) * HW + hw0 + p] = q.x;
                out[((size_t)b * CC + c0 + r * 4 + 1) * HW + hw0 + p] = q.y;
                out[((size_t)b * CC + c0 + r * 4 + 2) * HW + hw0 + p] = q.z;
                out[((size_t)b * CC + c0 + r * 4 + 3) * HW + hw0 + p] = q.w;
            }
        }
    }
}

// 16 fp64 terms of u += e*(2z - e) for one float4-quad j
#define ACCQ(U, V, J)                                                         \
  { double a0_ = (double)(V).x, a1_ = (double)(V).y,                          \
           a2_ = (double)(V).z, a3_ = (double)(V).w;                          \
    U = fma(a0_, zd2[(J)*4+0] - a0_, U);                                      \
    U = fma(a1_, zd2[(J)*4+1] - a1_, U);                                      \
    U = fma(a2_, zd2[(J)*4+2] - a2_, U);                                      \
    U = fma(a3_, zd2[(J)*4+3] - a3_, U); }

// ---- fp64 exact re-check of near-ties: BLOCK per item (4 waves split the
// 1024 codes), coalesced (rlane,dseg) layout, 2 row-groups in flight.
// u = 2 z.e - e^2 (fp64); max-u, lowest-k tie = exact argmin dist.
__global__ __launch_bounds__(256) void vq_refine(const float* __restrict__ x,
                                                 const float* __restrict__ embt,
                                                 float* __restrict__ out,
                                                 unsigned* __restrict__ hist,
                                                 const unsigned* __restrict__ wlcnt,
                                                 const int2* __restrict__ wl, int wlcap,
                                                 unsigned* __restrict__ fincnt,
                                                 const double* __restrict__ dsum) {
    __shared__ float  zrow[DD];
    __shared__ double wbest[4];
    __shared__ int    wbestk[4];
    __shared__ int    flip_s;
    __shared__ double fsum[256];
    const int t = threadIdx.x;
    const int w = t >> 6, l = t & 63;
    const int rlane = l >> 3;                   // row within 8-row group
    const int dseg  = l & 7;                    // 16-float segment of the row

    unsigned wc = *wlcnt;
    int nitems = (int)(wc < (unsigned)wlcap ? wc : (unsigned)wlcap);

    for (int it = blockIdx.x; it < nitems; it += gridDim.x) {
        __syncthreads();                        // zrow/flip reuse guard
        int2 item = wl[it];
        int p = item.x, n = item.y;
        int b = p >> 10, hw = p & 1023;

        if (t < DD) zrow[t] = x[((size_t)b * CC + n * DD + t) * HW + hw];
        __syncthreads();

        double zd2[16];                         // 2*z for this lane's segment (exact)
        #pragma unroll
        for (int i = 0; i < 16; ++i) zd2[i] = 2.0 * (double)zrow[dseg * 16 + i];

        const float* en = embt + (size_t)n * KK * DD;
        double best = -INFINITY; int bestk = 0;
        const int rbase = w * 256;              // wave's 256-code span

        #pragma unroll 1
        for (int g0 = 0; g0 < 32; g0 += 2) {    // 2 groups (16 rows) in flight
            const int rowA = rbase + g0 * 8 + rlane;
            const int rowB = rowA + 8;
            const float4* erA = (const float4*)(en + (size_t)rowA * DD + dseg * 16);
            const float4* erB = (const float4*)(en + (size_t)rowB * DD + dseg * 16);
            float4 va0 = erA[0], va1 = erA[1], va2 = erA[2], va3 = erA[3];
            float4 vb0 = erB[0], vb1 = erB[1], vb2 = erB[2], vb3 = erB[3];
            double uA = 0.0, uB = 0.0;
            ACCQ(uA, va0, 0) ACCQ(uA, va1, 1) ACCQ(uA, va2, 2) ACCQ(uA, va3, 3)
            ACCQ(uB, vb0, 0) ACCQ(uB, vb1, 1) ACCQ(uB, vb2, 2) ACCQ(uB, vb3, 3)
            // reduce each over the 8 dseg-lanes
            uA += __shfl_xor(uA, 1); uB += __shfl_xor(uB, 1);
            uA += __shfl_xor(uA, 2); uB += __shfl_xor(uB, 2);
            uA += __shfl_xor(uA, 4); uB += __shfl_xor(uB, 4);
            if (uA > best) { best = uA; bestk = rowA; }   // ascending rows =>
            if (uB > best) { best = uB; bestk = rowB; }   // strict > keeps first-min
        }
        // merge the 8 row-streams (rlane bits 8,16,32)
        #pragma unroll
        for (int mask = 8; mask <= 32; mask <<= 1) {
            double ob = __shfl_xor(best, mask);
            int    ok = __shfl_xor(bestk, mask);
            if (ob > best || (ob == best && ok < bestk)) { best = ob; bestk = ok; }
        }
        if (l == 0) { wbest[w] = best; wbestk[w] = bestk; }
        __syncthreads();
        if (t == 0) {                           // merge 4 waves (ascending k ranges)
            double m = wbest[0]; int mk = wbestk[0];
            #pragma unroll
            for (int ww = 1; ww < 4; ++ww)
                if (wbest[ww] > m) { m = wbest[ww]; mk = wbestk[ww]; }
            size_t slot = OFF_ARG + (size_t)b * (NN * HW) + (size_t)n * HW + hw;
            int oldk = (int)out[slot];
            flip_s = -1;
            if (mk != oldk) {
                out[slot] = (float)mk;
                atomicSub(&hist[n * KK + oldk], 1u);
                atomicAdd(&hist[n * KK + mk], 1u);
                flip_s = mk;
            }
        }
        __syncthreads();
        int fk = flip_s;
        if (fk >= 0 && t < DD)                  // rewrite stale z_q row
            out[((size_t)b * CC + n * DD + t) * HW + hw] = en[(size_t)fk * DD + t];
    }

    // ---- last-block-done: compute ppl + diff (fused final)
    __syncthreads();
    __threadfence();
    __shared__ unsigned rank_s;
    if (t == 0) rank_s = atomicAdd(fincnt, 1u);
    __syncthreads();
    if (rank_s == gridDim.x - 1) {
        __shared__ double hn[NN];
        for (int n = 0; n < NN; ++n) {
            double acc = 0.0;
            for (int k = t; k < KK; k += 256) {
                unsigned hv = atomicAdd(&hist[n * KK + k], 0u);   // coherent read
                double pr = (double)hv / (double)PP;
                acc += pr * log(pr + 1e-10);
            }
            fsum[t] = acc;
            __syncthreads();
            for (int off = 128; off > 0; off >>= 1) {
                if (t < off) fsum[t] += fsum[t + off];
                __syncthreads();
            }
            if (t == 0) hn[n] = fsum[0];
            __syncthreads();
        }
        if (t == 0) {
            double ppl = 0.0;
            for (int n = 0; n < NN; ++n) ppl += exp(-hn[n]);
            out[OFF_PPL]  = (float)(ppl * 0.25);
            out[OFF_DIFF] = (float)(*dsum / (double)((size_t)BB * CC * HW));
        }
    }
}

extern "C" void kernel_launch(void* const* d_in, const int* in_sizes, int n_in,
                              void* d_out, int out_size, void* d_ws, size_t ws_size,
                              hipStream_t stream) {
    const float* x     = (const float*)d_in[0];
    const float* embed = (const float*)d_in[1];
    float* out = (float*)d_out;
    char*  ws  = (char*)d_ws;

    unsigned* hist   = (unsigned*)(ws + WS_HIST);
    double*   dsum   = (double*)  (ws + WS_DSUM);
    unsigned* wlcnt  = (unsigned*)(ws + WS_WLCNT);
    unsigned* fincnt = (unsigned*)(ws + WS_FIN);
    float*    enorm  = (float*)   (ws + WS_ENORM);
    char*     ebf    = ws + WS_EBF;
    float*    embt   = (float*)   (ws + WS_EMBT);
    int2*     wl     = (int2*)    (ws + WS_WL);

    long long cap = ((long long)ws_size - WS_WL) / (long long)sizeof(int2);
    int wlcap = cap < 0 ? 0 : (cap > 65536 ? 65536 : (int)cap);

    vq_prep  <<<64,   256, 0, stream>>>(embed, ebf, embt, enorm, hist, dsum, wlcnt, fincnt);
    vq_main  <<<1024, 256, 0, stream>>>(x, ebf, embt, enorm, out, hist, dsum, wlcnt, wl, wlcap);
    vq_refine<<<2048, 256, 0, stream>>>(x, embt, out, hist, wlcnt, wl, wlcap, fincnt, dsum);
}

// Round 11
// 314.796 us; speedup vs baseline: 1.4734x; 1.4734x over previous
//
#include <hip/hip_runtime.h>
#include <math.h>

#define BB  64
#define CC  512
#define NN  4
#define KK  1024
#define DD  128
#define HW  1024
#define PP  65536

// d_out layout (float32, concatenated in return order)
#define OFF_DIFF 33554432UL
#define OFF_ARG  33554433UL
#define OFF_PPL  33816577UL

// d_ws layout (bytes)
#define WS_HIST   0
#define WS_DSUM   16384
#define WS_WLCNT  16392
#define WS_ENORM  16416
#define WS_EBF    32800                          // 128 tiles * 8192 B = 1 MiB (pre-swizzled fp16 eh, 32 codes x 128 d)
#define WS_EMBT   (32800 + 128*8192)             // fp32 embed_t[n][k][d], 2 MiB
#define WS_WL     (WS_EMBT + NN*KK*DD*4)

#define DELTA 0.0625f   // near-tie margin (dist space) -> fp64 re-check

typedef _Float16 half8 __attribute__((ext_vector_type(8)));
typedef float f32x4 __attribute__((ext_vector_type(4)));

#define MFMA16(a, b, c) __builtin_amdgcn_mfma_f32_16x16x32_f16(a, b, c, 0, 0, 0)

// swizzled byte offset for [row][128 fp16] tiles (256B rows): XOR 16B-slot with row&15
__device__ __forceinline__ int swz(int row, int dbyte) {
    return (row * 256 + dbyte) ^ ((row & 15) << 4);
}
__device__ __forceinline__ void gl2lds16(const void* g, void* l) {
    __builtin_amdgcn_global_load_lds(
        (const __attribute__((address_space(1))) unsigned int*)g,
        (__attribute__((address_space(3))) unsigned int*)l, 16, 0, 0);
}

// ---- prep: embed -> pre-swizzled fp16 tiles + fp32 embed_t + (-enorm/2) ----
__global__ __launch_bounds__(256) void vq_prep(const float* __restrict__ embed,
                                               char* __restrict__ ebf,
                                               float* __restrict__ embt,
                                               float* __restrict__ enorm,
                                               unsigned* __restrict__ hist,
                                               double* __restrict__ dsum,
                                               unsigned* __restrict__ wlcnt) {
    __shared__ float sred[4][64];
    const int e = blockIdx.x, n = e >> 4, kt = e & 15, k0 = kt * 64;
    const int t = threadIdx.x, kr = t & 63, dc = t >> 6;   // 4 d-chunks of 32
    if (t < 64) hist[e * 64 + t] = 0u;
    if (e == 0 && t == 0) { *dsum = 0.0; *wlcnt = 0u; }

    const float* src = embed + ((size_t)n * DD + dc * 32) * KK + k0 + kr;
    char* tile = ebf + ((size_t)(n * 32 + kt * 2 + (kr >> 5))) * 8192;
    const int row = kr & 31;
    float fv[32];
    #pragma unroll
    for (int r = 0; r < 32; ++r) fv[r] = src[(size_t)r * KK];
    float s = 0.f;
    #pragma unroll
    for (int j = 0; j < 4; ++j) {
        half8 vh;
        #pragma unroll
        for (int r = 0; r < 8; ++r) {
            float f = fv[j * 8 + r];
            vh[r] = (_Float16)f;
            s = fmaf(f, f, s);
        }
        *(half8*)(tile + swz(row, (dc * 32 + j * 8) * 2)) = vh;
    }
    {   // fp32 transposed codebook row for epilogue/refine
        float* drow = embt + ((size_t)n * KK + k0 + kr) * DD + dc * 32;
        #pragma unroll
        for (int j = 0; j < 8; ++j)
            *(float4*)(drow + j * 4) = make_float4(fv[j*4], fv[j*4+1], fv[j*4+2], fv[j*4+3]);
    }
    sred[dc][kr] = s;
    __syncthreads();
    if (t < 64) enorm[n * KK + k0 + t] =
        -0.5f * ((sred[0][t] + sred[1][t]) + (sred[2][t] + sred[3][t]));
}

// top-2 (MAX semantics on acc = z.e - e2/2; dist = -2*acc); static indices
#define TOP2(C0, C1, MF, KP)                                                  \
    _Pragma("unroll")                                                         \
    for (int i_ = 0; i_ < 4; ++i_) {                                          \
        float v_ = C0[i_] + C1[i_];                                           \
        int r_ = (MF) * 4 + i_;                                               \
        float mn_ = fminf(pb1[r_], v_);                                       \
        pb2[r_] = fmaxf(pb2[r_], mn_);                                        \
        pk1[r_] = (v_ > pb1[r_]) ? (KP) : pk1[r_];                            \
        pb1[r_] = fmaxf(pb1[r_], v_);                                         \
    }

// one tile step: stage-first (issue early), ds_read B, 8 MFMA -> ACW, TOP2(ACR prev)
#define VSTEP(ACW, ACR, KTL, KPREV)                                           \
  {                                                                           \
    if (gW < 128) {                                                           \
        const char* s_ = ebf + (size_t)gW * 8192 + t * 16;                    \
        char* d_ = ebase + (bufW << 13) + t * 16;                             \
        gl2lds16(s_, d_);                                                     \
        gl2lds16(s_ + 4096, d_ + 4096);                                       \
    }                                                                         \
    ++gW; bufW = (bufW == 5) ? 0 : bufW + 1;                                  \
    const int rb_ = bufR << 13;                                               \
    bufR = (bufR == 5) ? 0 : bufR + 1;                                        \
    half8 bh0 = *(const half8*)(ebase + rb_ + bo0);                           \
    half8 bh1 = *(const half8*)(ebase + rb_ + bo1);                           \
    half8 bh2 = *(const half8*)(ebase + rb_ + bo2);                           \
    half8 bh3 = *(const half8*)(ebase + rb_ + bo3);                           \
    float e2a = enls[((KTL) << 5) + koff];                                    \
    f32x4 e2v = {e2a, e2a, e2a, e2a};                                         \
    ACW##00 = MFMA16(af[0][0], bh0, e2v);                                     \
    ACW##00 = MFMA16(af[0][1], bh1, ACW##00);                                 \
    ACW##01 = MFMA16(af[0][2], bh2, zz4);                                     \
    ACW##01 = MFMA16(af[0][3], bh3, ACW##01);                                 \
    ACW##10 = MFMA16(af[1][0], bh0, e2v);                                     \
    ACW##10 = MFMA16(af[1][1], bh1, ACW##10);                                 \
    ACW##11 = MFMA16(af[1][2], bh2, zz4);                                     \
    ACW##11 = MFMA16(af[1][3], bh3, ACW##11);                                 \
    TOP2(ACR##00, ACR##01, 0, KPREV);                                         \
    TOP2(ACR##10, ACR##11, 1, KPREV);                                         \
  }

// ---- main ------------------------------------------------------------------
// 64 pos/block, 256 thr = 4 waves (2 p-halves x 2 k-halves); 6 LDS e-buffers,
// prefetch distance 4, one barrier + counted vmcnt per 2 tiles; acc ping-pong.
// Tail: FINAL window (n==3, wnd==15) has <=4 outstanding loads -> vmcnt(0) there.
__global__ __launch_bounds__(256, 2) void vq_main(const float* __restrict__ x,
                                                  const char* __restrict__ ebf,
                                                  const float* __restrict__ embt,
                                                  const float* __restrict__ enormg,
                                                  float* __restrict__ out,
                                                  unsigned* __restrict__ hist,
                                                  double* __restrict__ dsum,
                                                  unsigned* __restrict__ wlcnt,
                                                  int2* __restrict__ wl, int wlcap) {
    __shared__ __attribute__((aligned(16))) _Float16 zs[64 * 128];      // 16KB
    __shared__ __attribute__((aligned(16))) char ebuf[6][8192];         // 48KB
    __shared__ __attribute__((aligned(16))) float enls[KK];             // 4KB (-enorm/2)
    __shared__ int   idx_s[NN][64];
    __shared__ float red_b1[2][64], red_b2[2][64];
    __shared__ int   red_k1[2][64];
    __shared__ float wsum[4];

    const int t   = threadIdx.x;
    const int blk = blockIdx.x;                 // 1024 blocks: 16 per batch
    const int b   = blk >> 4;
    const int hw0 = (blk & 15) << 6;            // 64 consecutive positions
    const int w  = t >> 6, l = t & 63;
    const int pq = w >> 1;                      // p-half (32 rows)
    const int ks = w & 1;                       // k-half (16 of 32 per tile)
    const int tk = l & 15, lg = l >> 4;
    const int koff = ks * 16 + tk;

    char* ebase = (char*)&ebuf[0][0];
    const int bo0 = swz(koff, (0 * 32 + lg * 8) * 2);
    const int bo1 = swz(koff, (1 * 32 + lg * 8) * 2);
    const int bo2 = swz(koff, (2 * 32 + lg * 8) * 2);
    const int bo3 = swz(koff, (3 * 32 + lg * 8) * 2);

    const f32x4 zz4 = {0.f, 0.f, 0.f, 0.f};
    const f32x4 m1e30 = {-1e30f, -1e30f, -1e30f, -1e30f};

    int bufR = 0, bufW = 4, gW = 4;             // tile g -> buffer g%6, maintained incrementally
    float znacc = 0.f, sumb1 = 0.f;

    for (int n = 0; n < NN; ++n) {
        __syncthreads();                        // (A) zs/enls/red/idx reuse guard
        // stage -enorm/2 slice for this n (4KB)
        gl2lds16((const char*)(enormg + n * KK) + t * 16, (char*)enls + t * 16);
        if (n == 0) {                           // prologue: tiles 0..3 -> bufs 0..3
            #pragma unroll
            for (int j = 0; j < 4; ++j) {
                const char* s_ = ebf + (size_t)j * 8192 + t * 16;
                char* d_ = ebase + j * 8192 + t * 16;
                gl2lds16(s_, d_);
                gl2lds16(s_ + 4096, d_ + 4096);
            }
        }
        // ---- stage z (fp32 -> fp16 single-term, swizzled)
        {
            const int p = t & 63, dchunk = t >> 6;
            const float* xp = x + ((size_t)b * CC + n * DD + dchunk * 32) * HW + hw0 + p;
            float fv[32];
            #pragma unroll
            for (int r = 0; r < 32; ++r) fv[r] = xp[(size_t)r * HW];
            #pragma unroll
            for (int j = 0; j < 4; ++j) {
                half8 vh;
                #pragma unroll
                for (int r = 0; r < 8; ++r) {
                    float f = fv[j * 8 + r];
                    vh[r] = (_Float16)f;
                    znacc = fmaf(f, f, znacc);
                }
                *(half8*)((char*)zs + swz(p, (dchunk * 32 + j * 8) * 2)) = vh;
            }
        }
        __syncthreads();                        // (B) full drain: zs+enls+tiles resident

        // ---- A-fragments in registers for the whole n (8 frags = 32 VGPR)
        half8 af[2][4];
        #pragma unroll
        for (int mf = 0; mf < 2; ++mf)
            #pragma unroll
            for (int ds = 0; ds < 4; ++ds)
                af[mf][ds] = *(const half8*)((const char*)zs +
                               swz(pq * 32 + mf * 16 + tk, (ds * 32 + lg * 8) * 2));

        float pb1[8], pb2[8]; int pk1[8];       // r = mf*4+i -> p = pq*32+mf*16+lg*4+i
        #pragma unroll
        for (int r = 0; r < 8; ++r) { pb1[r] = -INFINITY; pb2[r] = -INFINITY; pk1[r] = 0; }

        f32x4 accA00, accA01, accA10, accA11;
        f32x4 accB00 = m1e30, accB01 = m1e30, accB10 = m1e30, accB11 = m1e30;

        #pragma unroll 1
        for (int wnd = 0; wnd < 16; ++wnd) {
            if (n == NN - 1 && wnd == 15)
                asm volatile("s_waitcnt vmcnt(0)" ::: "memory");   // tail: nothing left staging
            else
                asm volatile("s_waitcnt vmcnt(4)" ::: "memory");   // completes the 2 tiles read below
            __builtin_amdgcn_s_barrier();
            __builtin_amdgcn_sched_barrier(0);
            const int ka = wnd * 2;
            VSTEP(accA, accB, ka,     ((ka - 1) << 5) + koff)
            VSTEP(accB, accA, ka + 1, (ka << 5) + koff)
        }
        TOP2(accB00, accB01, 0, (31 << 5) + koff);   // drain tile 31
        TOP2(accB10, accB11, 1, (31 << 5) + koff);

        // ---- merge across the 16 lane-columns (tk) of the wave (max semantics)
        #pragma unroll
        for (int off = 1; off < 16; off <<= 1) {
            #pragma unroll
            for (int r = 0; r < 8; ++r) {
                float ob1 = __shfl_xor(pb1[r], off);
                float ob2 = __shfl_xor(pb2[r], off);
                int   ok1 = __shfl_xor(pk1[r], off);
                float nb2 = fmaxf(pb2[r], ob2);
                if (ob1 > pb1[r] || (ob1 == pb1[r] && ok1 < pk1[r])) {
                    pb2[r] = fmaxf(nb2, pb1[r]); pb1[r] = ob1; pk1[r] = ok1;
                } else {
                    pb2[r] = fmaxf(nb2, ob1);
                }
            }
        }
        if (tk == 0) {
            #pragma unroll
            for (int mf = 0; mf < 2; ++mf)
                #pragma unroll
                for (int i = 0; i < 4; ++i) {
                    int p = pq * 32 + mf * 16 + lg * 4 + i, r = mf * 4 + i;
                    red_b1[ks][p] = pb1[r]; red_b2[ks][p] = pb2[r]; red_k1[ks][p] = pk1[r];
                }
        }
        __syncthreads();
        if (t < 64) {                           // merge the 2 k-halves
            int p = t;
            float m1 = red_b1[0][p], m2 = red_b2[0][p]; int mk = red_k1[0][p];
            {
                float ob1 = red_b1[1][p], ob2 = red_b2[1][p]; int ok = red_k1[1][p];
                float nb2 = fmaxf(m2, ob2);
                if (ob1 > m1 || (ob1 == m1 && ok < mk)) { m2 = fmaxf(nb2, m1); m1 = ob1; mk = ok; }
                else                                    { m2 = fmaxf(nb2, ob1); }
            }
            idx_s[n][p] = mk;
            atomicAdd(&hist[n * KK + mk], 1u);
            sumb1 += m1;                        // dist = -2*m1; diff adds znorm separately
            if ((m1 - m2) < DELTA * 0.5f) {     // dist margin = 2*(m1-m2)
                unsigned pos = atomicAdd(wlcnt, 1u);
                if ((int)pos < wlcap) wl[pos] = make_int2(b * HW + hw0 + p, n);
            }
        }
    }

    // ---- diff partial reduce
    {
        float tot = znacc - 2.f * sumb1;
        #pragma unroll
        for (int off = 32; off > 0; off >>= 1) tot += __shfl_down(tot, off);
        if (l == 0) wsum[w] = tot;
        __syncthreads();                        // also guards idx_s for epilogue
        if (t == 0) {
            double sd = 0.0;
            #pragma unroll
            for (int ww = 0; ww < 4; ++ww) sd += (double)wsum[ww];
            atomicAdd(dsum, sd);
        }
    }

    // ---- argmin output (as float)
    {
        int n2 = t >> 6, p = t & 63;
        out[OFF_ARG + (size_t)b * (NN * HW) + (size_t)n2 * HW + hw0 + p] = (float)idx_s[n2][p];
    }

    // ---- z_q gather: contiguous embed_t rows (L2-resident) + coalesced stores
    {
        const int p = t & 63, dchunk = t >> 6;
        #pragma unroll
        for (int n2 = 0; n2 < NN; ++n2) {
            int k = idx_s[n2][p];
            const float4* src = (const float4*)(embt + ((size_t)n2 * KK + k) * DD + dchunk * 32);
            const int c0 = n2 * 128 + dchunk * 32;
            #pragma unroll
            for (int r = 0; r < 8; ++r) {
                float4 q = src[r];
                out[((size_t)b * CC + c0 + r * 4 + 0) * HW + hw0 + p] = q.x;
                out[((size_t)b * CC + c0 + r * 4 + 1) * HW + hw0 + p] = q.y;
                out[((size_t)b * CC + c0 + r * 4 + 2) * HW + hw0 + p] = q.z;
                out[((size_t)b * CC + c0 + r * 4 + 3) * HW + hw0 + p] = q.w;
            }
        }
    }
}

// 16 fp64 terms of u += e*(2z - e) for one float4-quad j
#define ACCQ(U, V, J)                                                         \
  { double a0_ = (double)(V).x, a1_ = (double)(V).y,                          \
           a2_ = (double)(V).z, a3_ = (double)(V).w;                          \
    U = fma(a0_, zd2[(J)*4+0] - a0_, U);                                      \
    U = fma(a1_, zd2[(J)*4+1] - a1_, U);                                      \
    U = fma(a2_, zd2[(J)*4+2] - a2_, U);                                      \
    U = fma(a3_, zd2[(J)*4+3] - a3_, U); }

// ---- fp64 exact re-check of near-ties: BLOCK per item (4 waves split the
// 1024 codes), coalesced (rlane,dseg) layout, 2 row-groups in flight.
// u = 2 z.e - e^2 (fp64); max-u, lowest-k tie = exact argmin dist.
// NO grid-wide rendezvous here (moved back to vq_final): the 2048-block
// same-address fence+atomic tail cost ~270us by itself.
__global__ __launch_bounds__(256) void vq_refine(const float* __restrict__ x,
                                                 const float* __restrict__ embt,
                                                 float* __restrict__ out,
                                                 unsigned* __restrict__ hist,
                                                 const unsigned* __restrict__ wlcnt,
                                                 const int2* __restrict__ wl, int wlcap) {
    __shared__ float  zrow[DD];
    __shared__ double wbest[4];
    __shared__ int    wbestk[4];
    __shared__ int    flip_s;
    const int t = threadIdx.x;
    const int w = t >> 6, l = t & 63;
    const int rlane = l >> 3;                   // row within 8-row group
    const int dseg  = l & 7;                    // 16-float segment of the row

    unsigned wc = *wlcnt;
    int nitems = (int)(wc < (unsigned)wlcap ? wc : (unsigned)wlcap);

    for (int it = blockIdx.x; it < nitems; it += gridDim.x) {
        __syncthreads();                        // zrow/flip reuse guard
        int2 item = wl[it];
        int p = item.x, n = item.y;
        int b = p >> 10, hw = p & 1023;

        if (t < DD) zrow[t] = x[((size_t)b * CC + n * DD + t) * HW + hw];
        __syncthreads();

        double zd2[16];                         // 2*z for this lane's segment (exact)
        #pragma unroll
        for (int i = 0; i < 16; ++i) zd2[i] = 2.0 * (double)zrow[dseg * 16 + i];

        const float* en = embt + (size_t)n * KK * DD;
        double best = -INFINITY; int bestk = 0;
        const int rbase = w * 256;              // wave's 256-code span

        #pragma unroll 1
        for (int g0 = 0; g0 < 32; g0 += 2) {    // 2 groups (16 rows) in flight
            const int rowA = rbase + g0 * 8 + rlane;
            const int rowB = rowA + 8;
            const float4* erA = (const float4*)(en + (size_t)rowA * DD + dseg * 16);
            const float4* erB = (const float4*)(en + (size_t)rowB * DD + dseg * 16);
            float4 va0 = erA[0], va1 = erA[1], va2 = erA[2], va3 = erA[3];
            float4 vb0 = erB[0], vb1 = erB[1], vb2 = erB[2], vb3 = erB[3];
            double uA = 0.0, uB = 0.0;
            ACCQ(uA, va0, 0) ACCQ(uA, va1, 1) ACCQ(uA, va2, 2) ACCQ(uA, va3, 3)
            ACCQ(uB, vb0, 0) ACCQ(uB, vb1, 1) ACCQ(uB, vb2, 2) ACCQ(uB, vb3, 3)
            // reduce each over the 8 dseg-lanes
            uA += __shfl_xor(uA, 1); uB += __shfl_xor(uB, 1);
            uA += __shfl_xor(uA, 2); uB += __shfl_xor(uB, 2);
            uA += __shfl_xor(uA, 4); uB += __shfl_xor(uB, 4);
            if (uA > best) { best = uA; bestk = rowA; }   // ascending rows =>
            if (uB > best) { best = uB; bestk = rowB; }   // strict > keeps first-min
        }
        // merge the 8 row-streams (rlane bits 8,16,32)
        #pragma unroll
        for (int mask = 8; mask <= 32; mask <<= 1) {
            double ob = __shfl_xor(best, mask);
            int    ok = __shfl_xor(bestk, mask);
            if (ob > best || (ob == best && ok < bestk)) { best = ob; bestk = ok; }
        }
        if (l == 0) { wbest[w] = best; wbestk[w] = bestk; }
        __syncthreads();
        if (t == 0) {                           // merge 4 waves (ascending k ranges)
            double m = wbest[0]; int mk = wbestk[0];
            #pragma unroll
            for (int ww = 1; ww < 4; ++ww)
                if (wbest[ww] > m) { m = wbest[ww]; mk = wbestk[ww]; }
            size_t slot = OFF_ARG + (size_t)b * (NN * HW) + (size_t)n * HW + hw;
            int oldk = (int)out[slot];
            flip_s = -1;
            if (mk != oldk) {
                out[slot] = (float)mk;
                atomicSub(&hist[n * KK + oldk], 1u);
                atomicAdd(&hist[n * KK + mk], 1u);
                flip_s = mk;
            }
        }
        __syncthreads();
        int fk = flip_s;
        if (fk >= 0 && t < DD)                  // rewrite stale z_q row
            out[((size_t)b * CC + n * DD + t) * HW + hw] = en[(size_t)fk * DD + t];
    }
}

// ---- final: ppl + diff (separate tiny launch; plain hist reads -------------
// kernel-boundary coherence makes refine's atomics visible)
__global__ __launch_bounds__(256) void vq_final(const unsigned* __restrict__ hist,
                                                const double* __restrict__ dsum,
                                                float* __restrict__ out) {
    __shared__ double red[256];
    __shared__ double hn[NN];
    const int t = threadIdx.x;
    for (int n = 0; n < NN; ++n) {
        double acc = 0.0;
        for (int k = t; k < KK; k += 256) {
            double pr = (double)hist[n * KK + k] / (double)PP;
            acc += pr * log(pr + 1e-10);
        }
        red[t] = acc;
        __syncthreads();
        for (int off = 128; off > 0; off >>= 1) {
            if (t < off) red[t] += red[t + off];
            __syncthreads();
        }
        if (t == 0) hn[n] = red[0];
        __syncthreads();
    }
    if (t == 0) {
        double ppl = 0.0;
        for (int n = 0; n < NN; ++n) ppl += exp(-hn[n]);
        out[OFF_PPL]  = (float)(ppl * 0.25);
        out[OFF_DIFF] = (float)(*dsum / (double)((size_t)BB * CC * HW));
    }
}

extern "C" void kernel_launch(void* const* d_in, const int* in_sizes, int n_in,
                              void* d_out, int out_size, void* d_ws, size_t ws_size,
                              hipStream_t stream) {
    const float* x     = (const float*)d_in[0];
    const float* embed = (const float*)d_in[1];
    float* out = (float*)d_out;
    char*  ws  = (char*)d_ws;

    unsigned* hist   = (unsigned*)(ws + WS_HIST);
    double*   dsum   = (double*)  (ws + WS_DSUM);
    unsigned* wlcnt  = (unsigned*)(ws + WS_WLCNT);
    float*    enorm  = (float*)   (ws + WS_ENORM);
    char*     ebf    = ws + WS_EBF;
    float*    embt   = (float*)   (ws + WS_EMBT);
    int2*     wl     = (int2*)    (ws + WS_WL);

    long long cap = ((long long)ws_size - WS_WL) / (long long)sizeof(int2);
    int wlcap = cap < 0 ? 0 : (cap > 65536 ? 65536 : (int)cap);

    vq_prep  <<<64,   256, 0, stream>>>(embed, ebf, embt, enorm, hist, dsum, wlcnt);
    vq_main  <<<1024, 256, 0, stream>>>(x, ebf, embt, enorm, out, hist, dsum, wlcnt, wl, wlcap);
    vq_refine<<<2048, 256, 0, stream>>>(x, embt, out, hist, wlcnt, wl, wlcap);
    vq_final <<<1,    256, 0, stream>>>(hist, dsum, out);
}